// Round 1
// baseline (1336.522 us; speedup 1.0000x reference)
//
#include <hip/hip_runtime.h>
#include <hip/hip_bf16.h>

typedef __attribute__((ext_vector_type(8))) short bhalf8;
typedef __attribute__((ext_vector_type(4))) float floatx4;

__device__ __forceinline__ unsigned short f2bf(float f) {
    unsigned int u = __float_as_uint(f);
    u += 0x7fffu + ((u >> 16) & 1u);
    return (unsigned short)(u >> 16);
}
__device__ __forceinline__ float bf2f(unsigned short h) {
    return __uint_as_float(((unsigned int)h) << 16);
}

// ---------------------------------------------------------------------------
// Pack W (K, CI, 128) f32 row-major -> bf16 in B-fragment order:
// packed[(((k*NC + c)*8 + g)*64 + l)*8 + b] = W[k][c*32 + (l>>4)*8 + b][g*16 + (l&15)]
// so each lane's 8 B-elements are 16 contiguous bytes.
// ---------------------------------------------------------------------------
__global__ __launch_bounds__(256) void pack_weights(const float* __restrict__ W,
                                                    unsigned short* __restrict__ out,
                                                    int K, int CI) {
    int t = blockIdx.x * 256 + threadIdx.x;
    int total = K * CI * 128;
    if (t >= total) return;
    int NC = CI >> 5;
    int b = t & 7;
    int l = (t >> 3) & 63;
    int g = (t >> 9) & 7;
    int rest = t >> 12;        // k*NC + c
    int c = rest % NC;
    int k = rest / NC;
    int ci = c * 32 + ((l >> 4) << 3) + b;
    int co = (g << 4) + (l & 15);
    out[t] = f2bf(W[((size_t)(k * CI + ci)) * 128 + co]);
}

// ---------------------------------------------------------------------------
// stats[0:128]=sum, stats[128:256]=sumsq -> st[0:128]=scale, st[128:256]=shift
// ---------------------------------------------------------------------------
__global__ void finalize_stats(const float* __restrict__ stats, float inv_n,
                               const float* __restrict__ g, const float* __restrict__ b,
                               float* __restrict__ st) {
    int c = threadIdx.x;   // 128 threads
    float mean = stats[c] * inv_n;
    float var = stats[128 + c] * inv_n - mean * mean;
    if (var < 0.f) var = 0.f;
    float s = g[c] * rsqrtf(var + 1e-5f);
    st[c] = s;
    st[128 + c] = fmaf(-mean, s, b[c]);
}

// ---------------------------------------------------------------------------
// resA = bn(Y2; stY) + bn(X2; stX); write f32 to outA and bf16 to outAb
// ---------------------------------------------------------------------------
__global__ __launch_bounds__(256) void combine_kernel(
    const unsigned short* __restrict__ Y2, const unsigned short* __restrict__ X2,
    const float* __restrict__ stY, const float* __restrict__ stX,
    float* __restrict__ outA, unsigned short* __restrict__ outAb, long total) {
    long i = (long)blockIdx.x * 256 + threadIdx.x;
    long base = i * 8;
    if (base >= total) return;
    int c0 = (int)(base & 127);
    bhalf8 y = *(const bhalf8*)(Y2 + base);
    bhalf8 x = *(const bhalf8*)(X2 + base);
    float v[8];
    bhalf8 ob;
#pragma unroll
    for (int j = 0; j < 8; ++j) {
        float fy = bf2f((unsigned short)y[j]);
        float fx = bf2f((unsigned short)x[j]);
        float r = fmaf(fy, stY[c0 + j], stY[128 + c0 + j]) +
                  fmaf(fx, stX[c0 + j], stX[128 + c0 + j]);
        v[j] = r;
        ob[j] = (short)f2bf(r);
    }
    float4 o0 = make_float4(v[0], v[1], v[2], v[3]);
    float4 o1 = make_float4(v[4], v[5], v[6], v[7]);
    *(float4*)(outA + base) = o0;
    *(float4*)(outA + base + 4) = o1;
    *(bhalf8*)(outAb + base) = ob;
}

// ---------------------------------------------------------------------------
// Gather-GEMM sparse conv. 64 output rows x 128 cols per block, 4 waves.
// mfma_f32_16x16x32_bf16; A staged in LDS per tap (XOR-swizzled); B from
// packed weights (L2-hot). Optional: scale/shift on gather (lazy BN of the
// previous layer), LReLU + batch-stat atomics in epilogue.
// ---------------------------------------------------------------------------
template <int CIN, int KT, bool SRC_F32, bool APPLY_ST, bool ACT_STATS, bool OUT_F32>
__global__ __launch_bounds__(256) void spconv_kernel(
    const void* __restrict__ srcv, const int* __restrict__ kmap,
    const unsigned short* __restrict__ Wp, const float* __restrict__ st,
    float* __restrict__ stats, void* __restrict__ outv, int Mout) {
    constexpr int NC = CIN / 32;          // k-chunks of 32
    constexpr int ROWB = CIN * 2;         // bytes per LDS row
    constexpr int ABYTES = 64 * ROWB;
    constexpr int OBYTES = OUT_F32 ? 64 * 128 * 4 : 64 * 128 * 2;
    constexpr int SBYTES = (ABYTES > OBYTES) ? ABYTES : OBYTES;

    __shared__ __align__(16) unsigned char s_buf[SBYTES];
    __shared__ int s_idx[KT * 64];
    __shared__ float s_st[2 * CIN];

    const int tid = threadIdx.x;
    const int lane = tid & 63;
    const int wid = tid >> 6;
    const int m0 = blockIdx.x * 64;

    for (int i = tid; i < KT * 64; i += 256) {
        int k = i >> 6, r = i & 63;
        int m = m0 + r;
        s_idx[i] = (m < Mout) ? kmap[(size_t)k * Mout + m] : -1;
    }
    if constexpr (APPLY_ST) {
        for (int i = tid; i < 2 * CIN; i += 256) s_st[i] = st[i];
    }
    __syncthreads();

    floatx4 acc[4][2];
#pragma unroll
    for (int i = 0; i < 4; ++i)
#pragma unroll
        for (int j = 0; j < 2; ++j) acc[i][j] = (floatx4){0.f, 0.f, 0.f, 0.f};

    for (int k = 0; k < KT; ++k) {
        if (k) __syncthreads();   // previous tap's MFMA done with s_buf
        // ---- gather tap k into LDS (swizzled) ----
        constexpr int CPR = CIN / 8;        // 16B chunks per row
        constexpr int RPP = 256 / CPR;      // rows per pass
#pragma unroll
        for (int p = 0; p < 64 / RPP; ++p) {
            int r = p * RPP + tid / CPR;
            int ch = tid % CPR;
            int idx = s_idx[k * 64 + r];
            unsigned off = (unsigned)(r * ROWB + ch * 16);
            off ^= (unsigned)((r & 7) << 4);
            bhalf8 val;
            if (idx >= 0) {
                if constexpr (SRC_F32) {
                    const float* sp = (const float*)srcv + (size_t)idx * CIN + ch * 8;
                    float4 lo = *(const float4*)sp;
                    float4 hi = *(const float4*)(sp + 4);
                    float f[8] = {lo.x, lo.y, lo.z, lo.w, hi.x, hi.y, hi.z, hi.w};
#pragma unroll
                    for (int j = 0; j < 8; ++j) val[j] = (short)f2bf(f[j]);
                } else {
                    const unsigned short* sp =
                        (const unsigned short*)srcv + (size_t)idx * CIN + ch * 8;
                    bhalf8 vsrc = *(const bhalf8*)sp;
                    if constexpr (APPLY_ST) {
                        int c0 = ch * 8;
#pragma unroll
                        for (int j = 0; j < 8; ++j) {
                            float x = bf2f((unsigned short)vsrc[j]);
                            x = fmaf(x, s_st[c0 + j], s_st[CIN + c0 + j]);
                            val[j] = (short)f2bf(x);
                        }
                    } else {
                        val = vsrc;
                    }
                }
            } else {
#pragma unroll
                for (int j = 0; j < 8; ++j) val[j] = 0;
            }
            *(bhalf8*)(s_buf + off) = val;
        }
        __syncthreads();
        // ---- MFMA over this tap ----
#pragma unroll
        for (int c = 0; c < NC; ++c) {
            bhalf8 a[4];
#pragma unroll
            for (int rg = 0; rg < 4; ++rg) {
                int row = rg * 16 + (lane & 15);
                unsigned off = (unsigned)(row * ROWB + (c * 32 + ((lane >> 4) * 8)) * 2);
                off ^= (unsigned)((row & 7) << 4);
                a[rg] = *(const bhalf8*)(s_buf + off);
            }
            bhalf8 b[2];
#pragma unroll
            for (int gg = 0; gg < 2; ++gg) {
                int g = wid * 2 + gg;
                size_t woff = ((((size_t)k * NC + c) * 8 + g) * 64 + lane) * 8;
                b[gg] = *(const bhalf8*)(Wp + woff);
            }
#pragma unroll
            for (int rg = 0; rg < 4; ++rg)
#pragma unroll
                for (int gg = 0; gg < 2; ++gg)
                    acc[rg][gg] = __builtin_amdgcn_mfma_f32_16x16x32_bf16(
                        a[rg], b[gg], acc[rg][gg], 0, 0, 0);
        }
    }
    __syncthreads();   // done with s_buf as A-tile

    // ---- epilogue: LReLU + stats + stage to LDS ----
    float sum[2] = {0.f, 0.f}, sq[2] = {0.f, 0.f};
#pragma unroll
    for (int rg = 0; rg < 4; ++rg) {
#pragma unroll
        for (int gg = 0; gg < 2; ++gg) {
            floatx4 v = acc[rg][gg];
            int col = wid * 32 + gg * 16 + (lane & 15);
#pragma unroll
            for (int j = 0; j < 4; ++j) {
                float x = v[j];
                if constexpr (ACT_STATS) {
                    x = (x >= 0.f) ? x : 0.01f * x;
                    sum[gg] += x;
                    sq[gg] += x * x;
                }
                int row = rg * 16 + ((lane >> 4) * 4) + j;
                if constexpr (OUT_F32)
                    ((float*)s_buf)[row * 128 + col] = x;
                else
                    ((unsigned short*)s_buf)[row * 128 + col] = f2bf(x);
            }
        }
    }
    if constexpr (ACT_STATS) {
#pragma unroll
        for (int gg = 0; gg < 2; ++gg) {
            float a1 = sum[gg], a2 = sq[gg];
            a1 += __shfl_xor(a1, 16); a2 += __shfl_xor(a2, 16);
            a1 += __shfl_xor(a1, 32); a2 += __shfl_xor(a2, 32);
            if ((lane >> 4) == 0) {
                int col = wid * 32 + gg * 16 + lane;
                atomicAdd(&stats[col], a1);
                atomicAdd(&stats[128 + col], a2);
            }
        }
    }
    __syncthreads();

    // ---- coalesced store ----
    int nrows = Mout - m0;
    if (nrows > 64) nrows = 64;
    if constexpr (OUT_F32) {
#pragma unroll
        for (int p = 0; p < 8; ++p) {
            int r = p * 8 + tid / 32, ch = tid % 32;
            if (r < nrows)
                ((float4*)outv)[(size_t)(m0 + r) * 32 + ch] =
                    ((const float4*)s_buf)[r * 32 + ch];
        }
    } else {
#pragma unroll
        for (int p = 0; p < 4; ++p) {
            int r = p * 16 + tid / 16, ch = tid % 16;
            if (r < nrows)
                ((bhalf8*)outv)[(size_t)(m0 + r) * 16 + ch] =
                    ((const bhalf8*)s_buf)[r * 16 + ch];
        }
    }
}

// ---------------------------------------------------------------------------
extern "C" void kernel_launch(void* const* d_in, const int* in_sizes, int n_in,
                              void* d_out, int out_size, void* d_ws, size_t ws_size,
                              hipStream_t stream) {
    const float* feats   = (const float*)d_in[0];
    const int* map31     = (const int*)d_in[1];
    const int* map13     = (const int*)d_in[2];
    const int* map_pool  = (const int*)d_in[3];
    const float* W1      = (const float*)d_in[4];
    const float* W1_2    = (const float*)d_in[5];
    const float* W2      = (const float*)d_in[6];
    const float* W3      = (const float*)d_in[7];
    const float* Wpool   = (const float*)d_in[8];
    const float* g0      = (const float*)d_in[9];
    const float* b0      = (const float*)d_in[10];
    const float* g0_2    = (const float*)d_in[11];
    const float* b0_2    = (const float*)d_in[12];
    const float* g1      = (const float*)d_in[13];
    const float* b1      = (const float*)d_in[14];
    const float* g2      = (const float*)d_in[15];
    const float* b2      = (const float*)d_in[16];

    const int N = in_sizes[0] / 64;
    const int M = in_sizes[3] / 27;

    // workspace layout
    unsigned char* ws = (unsigned char*)d_ws;
    const size_t S = (size_t)N * 128 * 2;      // one bf16 activation buffer
    unsigned short* bufA = (unsigned short*)(ws);           // X1 -> Y1 -> resA_bf16
    unsigned short* bufB = (unsigned short*)(ws + S);       // X2
    unsigned short* bufC = (unsigned short*)(ws + 2 * S);   // Y2
    unsigned short* W1p    = (unsigned short*)(ws + 3 * S);
    unsigned short* W12p   = W1p + 9 * 64 * 128;
    unsigned short* W2p    = W12p + 9 * 128 * 128;
    unsigned short* W3p    = W2p + 9 * 64 * 128;
    unsigned short* Wpoolp = W3p + 9 * 128 * 128;
    float* stats = (float*)(Wpoolp + 27 * 128 * 128);   // 4 x 256 floats
    float* stbuf = stats + 4 * 256;                     // 4 x 256 floats

    float* outB = (float*)d_out;                        // resB: M x 128
    float* outA = outB + (size_t)M * 128;               // resA: N x 128

    // zero the stats accumulators
    hipMemsetAsync(stats, 0, 4 * 256 * sizeof(float), stream);

    // pack weights to bf16 fragment order
    pack_weights<<<(9 * 64 * 128 + 255) / 256, 256, 0, stream>>>(W1, W1p, 9, 64);
    pack_weights<<<(9 * 128 * 128 + 255) / 256, 256, 0, stream>>>(W1_2, W12p, 9, 128);
    pack_weights<<<(9 * 64 * 128 + 255) / 256, 256, 0, stream>>>(W2, W2p, 9, 64);
    pack_weights<<<(9 * 128 * 128 + 255) / 256, 256, 0, stream>>>(W3, W3p, 9, 128);
    pack_weights<<<(27 * 128 * 128 + 255) / 256, 256, 0, stream>>>(Wpool, Wpoolp, 27, 128);

    const int gridN = (N + 63) / 64;
    const int gridM = (M + 63) / 64;
    const float inv_n = 1.0f / (float)N;

    // conv1 (3,1,3): X1 = lrelu(spconv(feats, map31, W1)); stats0
    spconv_kernel<64, 9, true, false, true, false><<<gridN, 256, 0, stream>>>(
        feats, map31, W1p, nullptr, stats + 0, bufA, N);
    finalize_stats<<<1, 128, 0, stream>>>(stats + 0, inv_n, g0, b0, stbuf + 0);

    // conv1_2 (1,3,3): X2 = lrelu(spconv(bn(X1), map13, W1_2)); stats1
    spconv_kernel<128, 9, false, true, true, false><<<gridN, 256, 0, stream>>>(
        bufA, map13, W12p, stbuf + 0, stats + 256, bufB, N);
    finalize_stats<<<1, 128, 0, stream>>>(stats + 256, inv_n, g0_2, b0_2, stbuf + 256);

    // conv2 (1,3,3): Y1 = lrelu(spconv(feats, map13, W2)); stats2   (bufA reused)
    spconv_kernel<64, 9, true, false, true, false><<<gridN, 256, 0, stream>>>(
        feats, map13, W2p, nullptr, stats + 512, bufA, N);
    finalize_stats<<<1, 128, 0, stream>>>(stats + 512, inv_n, g1, b1, stbuf + 512);

    // conv3 (3,1,3): Y2 = lrelu(spconv(bn(Y1), map31, W3)); stats3
    spconv_kernel<128, 9, false, true, true, false><<<gridN, 256, 0, stream>>>(
        bufA, map31, W3p, stbuf + 512, stats + 768, bufC, N);
    finalize_stats<<<1, 128, 0, stream>>>(stats + 768, inv_n, g2, b2, stbuf + 768);

    // resA = bn(Y2) + bn(X2) -> d_out (f32) + bufA (bf16)
    long totalA = (long)N * 128;
    combine_kernel<<<(unsigned)((totalA / 8 + 255) / 256), 256, 0, stream>>>(
        bufC, bufB, stbuf + 768, stbuf + 256, outA, bufA, totalA);

    // pool conv (27 taps, strided): resB = spconv(resA, map_pool, Wpool) -> f32
    spconv_kernel<128, 27, false, false, false, true><<<gridM, 256, 0, stream>>>(
        bufA, map_pool, Wpoolp, nullptr, nullptr, outB, M);
}